// Round 6
// baseline (434.614 us; speedup 1.0000x reference)
//
#include <hip/hip_runtime.h>

// MHConvAttention MFMA v8 (resubmit — R5 bench was GPUAcquisitionTimeout,
// change never measured). B=16, C=256, H=W=64, NH=8, hd=32, WS=5.
// v8 changes vs v7 (418.0 us; content_combine ~112 us, VALU 33%, HBM 10%):
//  - content_combine: restore cls LDS staging, now PRE-NORMALIZED
//    (cls[i][o] = cl[i][o] * 0.1767/S[i] folded at stage time). Content loop
//    becomes uniform ds_read_b128 broadcasts instead of 256 global
//    dwordx4 loads per thread (issue/latency bound).
//  - vt layout (v7) and conv/gemm (v6 m248 schedule) unchanged.
//
// Workspace layout (bytes), total 136,462,336:
//   [0)           qkv bf16 (65536,768)  100,663,296   ALIASED with:
//   [0)           xpad bf16 (16,66,66,256) 35,684,352 (dead after conv)
//   [100663296)   x / result bf16 (65536,256) 33,554,432
//   [134217728)   cl f32 (128,32,32)        524,288
//   [134742016)   S  f32 (128,32)            16,384
//   [134758400)   wrb bf16 (9,256,256)    1,179,648
//   [135938048)   wq  bf16 (768,256)        393,216
//   [136331264)   wo  bf16 (256,256)        131,072

typedef unsigned short u16;
typedef __bf16 bf16x8 __attribute__((ext_vector_type(8)));
typedef float f32x4 __attribute__((ext_vector_type(4)));
#define HW 4096

__device__ __forceinline__ float bf2f(u16 u){
  unsigned v = ((unsigned)u) << 16;
  return __builtin_bit_cast(float, v);
}
__device__ __forceinline__ u16 f2bf(float f){
  unsigned u = __builtin_bit_cast(unsigned, f);
  u = u + 0x7fffu + ((u >> 16) & 1u);   // RNE
  return (u16)(u >> 16);
}
__device__ __forceinline__ unsigned pack2(float a, float b){
  return (unsigned)f2bf(a) | ((unsigned)f2bf(b) << 16);
}
__device__ __forceinline__ void unpack2(unsigned u, float& a, float& b){
  a = bf2f((u16)(u & 0xffffu)); b = bf2f((u16)(u >> 16));
}
__device__ __forceinline__ void unp8(uint4 r, float* v){
  unpack2(r.x, v[0], v[1]); unpack2(r.y, v[2], v[3]);
  unpack2(r.z, v[4], v[5]); unpack2(r.w, v[6], v[7]);
}

__device__ __forceinline__ void gl2lds16(const u16* g, u16* l){
  __builtin_amdgcn_global_load_lds((__attribute__((address_space(1))) void*)g,
                                   (__attribute__((address_space(3))) void*)l, 16, 0, 0);
}

// ---------------- zero only the 1-px border of xpad ----------------
__global__ void zero_border(u16* __restrict__ xpad){
  int idx = blockIdx.x*256 + threadIdx.x;   // 133120 granules
  int g = idx & 31;
  int p = idx >> 5;                         // border px 0..4159
  int b = p / 260; int r = p - b*260;
  int y, x;
  if (r < 66)      { y = 0;      x = r; }
  else if (r < 132){ y = 65;     x = r-66; }
  else if (r < 196){ y = r-131;  x = 0; }
  else             { y = r-195;  x = 65; }
  *(uint4*)&xpad[((size_t)b*4356 + (size_t)y*66 + x)*256 + g*8] = uint4{0,0,0,0};
}

// ---------------- src NCHW f32 -> xpad NHWC bf16 (66x66, interior) ----------------
__global__ __launch_bounds__(256) void to_nhwc(const float* __restrict__ src,
                                               u16* __restrict__ xpad){
  __shared__ u16 sl[64*264];
  const int t = threadIdx.x, w = t>>6, lane = t&63;
  const int y = blockIdx.x, b = blockIdx.y;
  for (int cc = 0; cc < 64; ++cc){
    const int c = cc*4 + w;
    float v = src[((size_t)(b*256 + c))*HW + y*64 + lane];
    sl[lane*264 + c] = f2bf(v);
  }
  __syncthreads();
  #pragma unroll
  for (int i = 0; i < 8; ++i){
    int idx = t + 256*i;
    int p = idx >> 5, g = idx & 31;
    uint4 v = *(const uint4*)&sl[p*264 + g*8];
    *(uint4*)&xpad[((size_t)b*4356 + (size_t)(y+1)*66 + (p+1))*256 + g*8] = v;
  }
}

// ---------------- repack all weights to bf16 ----------------
__global__ void repack_w(const float* __restrict__ cpe_w, const float* __restrict__ qkv_w,
                         const float* __restrict__ out_w, u16* __restrict__ wrb,
                         u16* __restrict__ wq, u16* __restrict__ wo){
  int idx = blockIdx.x*256 + threadIdx.x;
  if (idx < 589824){
    int kk = idx >> 16, o = (idx >> 8) & 255, c = idx & 255;
    wrb[idx] = f2bf(cpe_w[((o*256 + c)*9) + kk]);
  } else if (idx < 786432){
    int j = idx - 589824;
    wq[j] = f2bf(qkv_w[j]);
  } else {
    int j = idx - 786432;
    wo[j] = f2bf(out_w[j]);
  }
}

// ---------------- CPE 3x3 conv: 256px x 256och tile, 8 waves, K=2304 ------------
// LDS [256 rows][64 ch] x2 bufs per matrix; granule slot g at row p holds logical
// granule g^(p&7) (pre-swizzled global source, linear LDS dest).
__global__ __launch_bounds__(512, 2) void conv_mfma(const u16* __restrict__ xpad,
    const u16* __restrict__ wrb, const float* __restrict__ bias,
    u16* __restrict__ xout){
  __shared__ u16 As[32768];            // 2 x [256 px][64 k] = 2 x 32 KB
  __shared__ u16 Bs[32768];            // 2 x [256 o][64 k]
  const int t = threadIdx.x, w8 = t>>6, lane = t&63;
  const int idx = blockIdx.x;          // 0..255, 1 block/CU
  const int nb = (idx&7)*32 + (idx>>3);        // XCD-contiguous pixel blocks
  const int pg = nb*256;
  const int b = pg>>12, row0 = (pg&4095)>>6;   // 4 rows per block
  const size_t xb = (size_t)b*4356;
  // staging: 4 issues/thread/matrix; granule G=(w8*4+i)*64+lane -> px G>>3, slot G&7
  const int dstb = w8*2048 + lane*8;   // u16 offset of issue-0 dest
  const u16* aP[4]; const u16* bP[4];
  #pragma unroll
  for (int i = 0; i < 4; ++i){
    int G = (w8*4+i)*64 + lane;
    int p = G>>3, gs = (G&7) ^ (p&7);
    aP[i] = xpad + (xb + (size_t)(row0 + (p>>6) + 1)*66 + (p&63) + 1)*256 + gs*8;
    bP[i] = wrb + (size_t)p*256 + gs*8;
  }
  const int wm = w8>>2, wn = w8&3;     // wave -> (px half, och quarter)
  const int qd = lane>>4;
  int a_off[8], b_off[4];
  #pragma unroll
  for (int m = 0; m < 8; ++m){
    int p = wm*128 + m*16 + (lane&15);
    a_off[m] = p*64 + ((qd ^ (p&7)) << 3);
  }
  #pragma unroll
  for (int n = 0; n < 4; ++n){
    int r = wn*64 + n*16 + (lane&15);
    b_off[n] = r*64 + ((qd ^ (r&7)) << 3);
  }
  f32x4 acc[8][4];
  #pragma unroll
  for (int i=0;i<8;++i)
    #pragma unroll
    for (int j=0;j<4;++j) acc[i][j] = f32x4{0.f,0.f,0.f,0.f};

  auto STAGE = [&](const int bufo, const int s){
    int c9 = s/9, tap = s - c9*9, ky = tap/3, kx = tap - ky*3;
    int offA = ((ky-1)*66 + (kx-1))*256 + c9*64;
    int offB = tap*65536 + c9*64;
    #pragma unroll
    for (int i = 0; i < 4; ++i){
      gl2lds16(aP[i] + offA, &As[bufo + dstb + i*512]);
      gl2lds16(bP[i] + offB, &Bs[bufo + dstb + i*512]);
    }
  };
  auto COMPUTE = [&](const int bufo){
    __builtin_amdgcn_s_setprio(1);
    #pragma unroll
    for (int kh = 0; kh < 2; ++kh){
      bf16x8 af[8], bfr[4];
      #pragma unroll
      for (int m = 0; m < 8; ++m)
        af[m] = __builtin_bit_cast(bf16x8, *(const uint4*)&As[bufo + (a_off[m] ^ (kh<<5))]);
      #pragma unroll
      for (int n = 0; n < 4; ++n)
        bfr[n] = __builtin_bit_cast(bf16x8, *(const uint4*)&Bs[bufo + (b_off[n] ^ (kh<<5))]);
      #pragma unroll
      for (int mt = 0; mt < 8; ++mt)
        #pragma unroll
        for (int nt = 0; nt < 4; ++nt)   // A=weights, B=pixels -> D[row=och][col=px]
          acc[mt][nt] = __builtin_amdgcn_mfma_f32_16x16x32_bf16(bfr[nt], af[mt], acc[mt][nt], 0,0,0);
    }
    __builtin_amdgcn_s_setprio(0);
  };
  #define SYNC asm volatile("s_waitcnt vmcnt(0)" ::: "memory"); __builtin_amdgcn_s_barrier();

  STAGE(0, 0);
  SYNC
  for (int s2 = 0; s2 < 18; ++s2){       // 36 K-steps, x2 unrolled (literal bufo)
    STAGE(16384, 2*s2+1);
    COMPUTE(0);
    SYNC
    if (s2 < 17) STAGE(0, 2*s2+2);
    COMPUTE(16384);
    SYNC
  }
  // epilogue: lane holds 4 consecutive och at one px -> 8-B stores
  #pragma unroll
  for (int nt = 0; nt < 4; ++nt){
    const int och4 = wn*64 + nt*16 + qd*4;
    float4 b4 = *(const float4*)&bias[och4];
    #pragma unroll
    for (int mt = 0; mt < 8; ++mt){
      const int px = wm*128 + mt*16 + (lane&15);
      const int y = row0 + (px>>6), x = px&63;
      ushort4 r4 = *(const ushort4*)&xpad[(xb + (size_t)(y+1)*66 + x + 1)*256 + och4];
      ushort4 s;
      s.x = f2bf(acc[mt][nt][0] + b4.x + bf2f(r4.x));
      s.y = f2bf(acc[mt][nt][1] + b4.y + bf2f(r4.y));
      s.z = f2bf(acc[mt][nt][2] + b4.z + bf2f(r4.z));
      s.w = f2bf(acc[mt][nt][3] + b4.w + bf2f(r4.w));
      *(ushort4*)&xout[(size_t)(pg + px)*256 + och4] = s;
    }
  }
  #undef SYNC
}

// ---------------- K=256 MFMA GEMM, 256x256 tile, 8 waves, m248 schedule. -------
// F32OUT=false: swapped operands, NHWC bf16 out. F32OUT=true: NCHW f32 out + bias.
template<int NO, int NOT, bool F32OUT>
__global__ __launch_bounds__(512, 2) void gemm_mfma(const u16* __restrict__ act,
    const u16* __restrict__ wt, const float* __restrict__ bias, void* __restrict__ out){
  __shared__ u16 As[32768];
  __shared__ u16 Bs[32768];
  const int t = threadIdx.x, w8 = t>>6, lane = t&63;
  const int idx = blockIdx.x;
  const int x8 = idx&7, q = idx>>3;
  const int ot = q % NOT, nb = x8*32 + q / NOT;
  const int pg = nb*256, o0 = ot*256;
  const int dstb = w8*2048 + lane*8;
  const u16* aP[4]; const u16* bP[4];
  #pragma unroll
  for (int i = 0; i < 4; ++i){
    int G = (w8*4+i)*64 + lane;
    int p = G>>3, gs = (G&7) ^ (p&7);
    aP[i] = act + (size_t)(pg + p)*256 + gs*8;
    bP[i] = wt  + (size_t)(o0 + p)*256 + gs*8;
  }
  const int wm = w8>>2, wn = w8&3;
  const int qd = lane>>4;
  int a_off[8], b_off[4];
  #pragma unroll
  for (int m = 0; m < 8; ++m){
    int p = wm*128 + m*16 + (lane&15);
    a_off[m] = p*64 + ((qd ^ (p&7)) << 3);
  }
  #pragma unroll
  for (int n = 0; n < 4; ++n){
    int r = wn*64 + n*16 + (lane&15);
    b_off[n] = r*64 + ((qd ^ (r&7)) << 3);
  }
  f32x4 acc[8][4];
  #pragma unroll
  for (int i=0;i<8;++i)
    #pragma unroll
    for (int j=0;j<4;++j) acc[i][j] = f32x4{0.f,0.f,0.f,0.f};

  auto STAGE = [&](const int bufo, const int s){
    const int c0 = s*64;
    #pragma unroll
    for (int i = 0; i < 4; ++i){
      gl2lds16(aP[i] + c0, &As[bufo + dstb + i*512]);
      gl2lds16(bP[i] + c0, &Bs[bufo + dstb + i*512]);
    }
  };
  auto COMPUTE = [&](const int bufo){
    __builtin_amdgcn_s_setprio(1);
    #pragma unroll
    for (int kh = 0; kh < 2; ++kh){
      bf16x8 af[8], bfr[4];
      #pragma unroll
      for (int m = 0; m < 8; ++m)
        af[m] = __builtin_bit_cast(bf16x8, *(const uint4*)&As[bufo + (a_off[m] ^ (kh<<5))]);
      #pragma unroll
      for (int n = 0; n < 4; ++n)
        bfr[n] = __builtin_bit_cast(bf16x8, *(const uint4*)&Bs[bufo + (b_off[n] ^ (kh<<5))]);
      #pragma unroll
      for (int mt = 0; mt < 8; ++mt)
        #pragma unroll
        for (int nt = 0; nt < 4; ++nt){
          if constexpr (F32OUT)
            acc[mt][nt] = __builtin_amdgcn_mfma_f32_16x16x32_bf16(af[mt], bfr[nt], acc[mt][nt], 0,0,0);
          else
            acc[mt][nt] = __builtin_amdgcn_mfma_f32_16x16x32_bf16(bfr[nt], af[mt], acc[mt][nt], 0,0,0);
        }
    }
    __builtin_amdgcn_s_setprio(0);
  };
  #define SYNC asm volatile("s_waitcnt vmcnt(0)" ::: "memory"); __builtin_amdgcn_s_barrier();

  STAGE(0, 0);
  SYNC
  for (int s2 = 0; s2 < 2; ++s2){        // 4 K-steps
    STAGE(16384, 2*s2+1);
    COMPUTE(0);
    SYNC
    if (s2 < 1) STAGE(0, 2*s2+2);
    COMPUTE(16384);
    SYNC
  }
  if constexpr (F32OUT){
    const int col = lane&15, row_l = qd*4;
    const int b = pg>>12, hw0 = pg&4095;
    float* op = (float*)out;
    #pragma unroll
    for (int nt = 0; nt < 4; ++nt){
      const int och = o0 + wn*64 + nt*16 + col;
      const float bo2 = bias[och];
      #pragma unroll
      for (int mt = 0; mt < 8; ++mt){
        const int pl = wm*128 + mt*16 + row_l;
        float4 v;
        v.x = acc[mt][nt][0]+bo2; v.y = acc[mt][nt][1]+bo2;
        v.z = acc[mt][nt][2]+bo2; v.w = acc[mt][nt][3]+bo2;
        *(float4*)&op[((size_t)b*256 + och)*HW + hw0 + pl] = v;
      }
    }
  } else {
    u16* op = (u16*)out;
    #pragma unroll
    for (int nt = 0; nt < 4; ++nt){
      const int och4 = o0 + wn*64 + nt*16 + qd*4;
      #pragma unroll
      for (int mt = 0; mt < 8; ++mt){
        const int px = wm*128 + mt*16 + (lane&15);
        ushort4 s;
        s.x = f2bf(acc[mt][nt][0]); s.y = f2bf(acc[mt][nt][1]);
        s.z = f2bf(acc[mt][nt][2]); s.w = f2bf(acc[mt][nt][3]);
        *(ushort4*)&op[(size_t)(pg + px)*NO + och4] = s;
      }
    }
  }
  #undef SYNC
}

__global__ void zero_cl(float* __restrict__ cl){
  cl[blockIdx.x*256 + threadIdx.x] = 0.f;   // zeros cl (131072) + S (4096)
}

// ---------------- lambda: cl'[b',i,o] = sum_n exp(k[n][i])*v[n][o]; S[b',i] = sum_n exp ----
__global__ __launch_bounds__(64) void lambda_kern(const u16* __restrict__ qkv,
                                                  float* __restrict__ cl,
                                                  float* __restrict__ S){
  __shared__ float Kl[64*36];
  __shared__ float Vl[64*36];
  const int t = threadIdx.x;
  const int bp = blockIdx.x, split = blockIdx.y;
  const int b = bp>>3, h = bp&7;
  const int ig = t&7, og = t>>3;
  float acc[4][4];
  float sacc[4] = {0.f,0.f,0.f,0.f};
  #pragma unroll
  for (int i=0;i<4;++i)
    #pragma unroll
    for (int j=0;j<4;++j) acc[i][j] = 0.f;
  for (int chunk = 0; chunk < 8; ++chunk){
    const int n = split*512 + chunk*64 + t;
    const u16* kp = qkv + (size_t)(b*HW + n)*768 + 256 + h*32;   // raw k
    const u16* vp = kp + 256;
    uint4 k4[4], v4[4];
    #pragma unroll
    for (int qq=0;qq<4;++qq){ k4[qq] = ((const uint4*)kp)[qq]; v4[qq] = ((const uint4*)vp)[qq]; }
    __syncthreads();
    #pragma unroll
    for (int qq=0;qq<4;++qq){
      float kv[8], vv[8]; unp8(k4[qq], kv); unp8(v4[qq], vv);
      #pragma unroll
      for (int e=0;e<8;++e) kv[e] = __expf(kv[e]);
      *(float4*)&Kl[t*36 + qq*8]     = float4{kv[0],kv[1],kv[2],kv[3]};
      *(float4*)&Kl[t*36 + qq*8 + 4] = float4{kv[4],kv[5],kv[6],kv[7]};
      *(float4*)&Vl[t*36 + qq*8]     = float4{vv[0],vv[1],vv[2],vv[3]};
      *(float4*)&Vl[t*36 + qq*8 + 4] = float4{vv[4],vv[5],vv[6],vv[7]};
    }
    __syncthreads();
    for (int p = 0; p < 64; ++p){
      float4 kf = *(const float4*)&Kl[p*36 + ig*4];
      float4 vf = *(const float4*)&Vl[p*36 + og*4];
      float kfa[4] = {kf.x,kf.y,kf.z,kf.w};
      float vfa[4] = {vf.x,vf.y,vf.z,vf.w};
      #pragma unroll
      for (int i=0;i<4;++i){
        sacc[i] += kfa[i];
        #pragma unroll
        for (int j=0;j<4;++j) acc[i][j] = fmaf(kfa[i], vfa[j], acc[i][j]);
      }
    }
  }
  #pragma unroll
  for (int i=0;i<4;++i)
    #pragma unroll
    for (int j=0;j<4;++j)
      atomicAdd(&cl[(size_t)bp*1024 + (ig*4+i)*32 + og*4+j], acc[i][j]);
  if (og == 0){
    #pragma unroll
    for (int i=0;i<4;++i) atomicAdd(&S[bp*32 + ig*4 + i], sacc[i]);
  }
}

// ---------------- fused content + depthwise-5x5 pos-lambda + combine ----------------
// vt layout: [chg 0..3][hp 0..399][8 u16] -> granule idx = chg*400 + hp.
// cls staged in LDS pre-normalized (0.1767/S folded); content loop reads are
// uniform ds_read_b128 broadcasts (conflict-free) instead of per-thread
// global dwordx4 chains.
__global__ __launch_bounds__(256) void content_combine(const u16* __restrict__ qkv,
    const float* __restrict__ cl, const float* __restrict__ S,
    const float* __restrict__ rel, u16* __restrict__ res){
  __shared__ u16 vt[12800];
  __shared__ float relT[800];
  __shared__ float cls[1024];
  const int t = threadIdx.x;
  const int tile = blockIdx.x, h = blockIdx.y, b = blockIdx.z;
  const int x0 = (tile&3)*16, y0 = (tile>>2)*16;
  for (int idx = t; idx < 1024; idx += 256){
    const float sinv = 0.17677669529663687f *
                       __builtin_amdgcn_rcpf(S[(b*8+h)*32 + (idx>>5)]);
    cls[idx] = cl[(size_t)(b*8+h)*1024 + idx] * sinv;
  }
  for (int idx = t; idx < 800; idx += 256){
    int tap = idx>>5, ch = idx&31;
    relT[idx] = rel[ch*25 + tap];
  }
  #pragma unroll
  for (int i = 0; i < 7; ++i){
    int idx = t + 256*i;
    if (idx < 1600){
      int hp = idx>>2, g = idx&3;
      int hy = hp/20, hx = hp - hy*20;
      int y = y0 + hy - 2, x = x0 + hx - 2;
      uint4 v = uint4{0,0,0,0};
      if ((unsigned)y < 64u && (unsigned)x < 64u)
        v = *(const uint4*)&qkv[(size_t)(b*HW + y*64 + x)*768 + 512 + h*32 + g*8];
      *(uint4*)&vt[(g*400 + hp)*8] = v;
    }
  }
  __syncthreads();
  const int py = t>>4, px = t&15;
  const int pix = b*HW + (y0+py)*64 + x0 + px;
  const u16* qp = qkv + (size_t)pix*768 + h*32;
  float qv[32];
  {
    uint4 q0 = ((const uint4*)qp)[0], q1 = ((const uint4*)qp)[1];
    uint4 q2 = ((const uint4*)qp)[2], q3 = ((const uint4*)qp)[3];
    unp8(q0, qv); unp8(q1, qv+8); unp8(q2, qv+16); unp8(q3, qv+24);
  }
  float outv[32];
  #pragma unroll
  for (int j=0;j<32;++j) outv[j] = 0.f;
  for (int i = 0; i < 32; ++i){
    const float qi = qv[i];          // 1/S and scale pre-folded into cls
    #pragma unroll
    for (int g = 0; g < 8; ++g){
      float4 c4 = *(const float4*)&cls[i*32 + g*4];
      outv[g*4+0] = fmaf(qi, c4.x, outv[g*4+0]);
      outv[g*4+1] = fmaf(qi, c4.y, outv[g*4+1]);
      outv[g*4+2] = fmaf(qi, c4.z, outv[g*4+2]);
      outv[g*4+3] = fmaf(qi, c4.w, outv[g*4+3]);
    }
  }
  #pragma unroll
  for (int chg = 0; chg < 4; ++chg){
    float pos[8];
    #pragma unroll
    for (int j=0;j<8;++j) pos[j] = 0.f;
    #pragma unroll
    for (int dy = 0; dy < 5; ++dy)
      #pragma unroll
      for (int dx = 0; dx < 5; ++dx){
        int hp = (py+dy)*20 + px + dx;
        uint4 v4 = *(const uint4*)&vt[(chg*400 + hp)*8];
        float vv[8]; unp8(v4, vv);
        float4 r0 = *(const float4*)&relT[(dy*5+dx)*32 + chg*8];
        float4 r1 = *(const float4*)&relT[(dy*5+dx)*32 + chg*8 + 4];
        pos[0]=fmaf(r0.x, vv[0], pos[0]); pos[1]=fmaf(r0.y, vv[1], pos[1]);
        pos[2]=fmaf(r0.z, vv[2], pos[2]); pos[3]=fmaf(r0.w, vv[3], pos[3]);
        pos[4]=fmaf(r1.x, vv[4], pos[4]); pos[5]=fmaf(r1.y, vv[5], pos[5]);
        pos[6]=fmaf(r1.z, vv[6], pos[6]); pos[7]=fmaf(r1.w, vv[7], pos[7]);
      }
    #pragma unroll
    for (int j=0;j<8;++j) outv[chg*8+j] = fmaf(qv[chg*8+j], pos[j], outv[chg*8+j]);
  }
  u16* rp = res + (size_t)pix*256 + h*32;
  #pragma unroll
  for (int g = 0; g < 4; ++g){
    uint4 o_;
    o_.x = pack2(outv[g*8+0], outv[g*8+1]);
    o_.y = pack2(outv[g*8+2], outv[g*8+3]);
    o_.z = pack2(outv[g*8+4], outv[g*8+5]);
    o_.w = pack2(outv[g*8+6], outv[g*8+7]);
    ((uint4*)rp)[g] = o_;
  }
}

extern "C" void kernel_launch(void* const* d_in, const int* in_sizes, int n_in,
                              void* d_out, int out_size, void* d_ws, size_t ws_size,
                              hipStream_t stream) {
  const float* src   = (const float*)d_in[0];
  const float* rel   = (const float*)d_in[1];
  const float* qkv_w = (const float*)d_in[2];
  const float* cpe_w = (const float*)d_in[3];
  const float* cpe_b = (const float*)d_in[4];
  const float* out_w = (const float*)d_in[5];
  const float* out_b = (const float*)d_in[6];
  char* ws = (char*)d_ws;
  u16*   qkv  = (u16*)(ws);
  u16*   xpad = (u16*)(ws);                    // aliased (dead after conv)
  u16*   xbuf = (u16*)(ws + 100663296);
  float* cl   = (float*)(ws + 134217728);
  float* S    = (float*)(ws + 134742016);
  u16*   wrb  = (u16*)(ws + 134758400);
  u16*   wq   = (u16*)(ws + 135938048);
  u16*   wo   = (u16*)(ws + 136331264);

  zero_border<<<dim3(520), dim3(256), 0, stream>>>(xpad);
  to_nhwc<<<dim3(64, 16), dim3(256), 0, stream>>>(src, xpad);
  repack_w<<<dim3(3328), dim3(256), 0, stream>>>(cpe_w, qkv_w, out_w, wrb, wq, wo);
  conv_mfma<<<dim3(256), dim3(512), 0, stream>>>(xpad, wrb, cpe_b, xbuf);
  gemm_mfma<768,3,false><<<dim3(768), dim3(512), 0, stream>>>(xbuf, wq, nullptr, (void*)qkv);
  zero_cl<<<dim3(528), dim3(256), 0, stream>>>(cl);   // zeros cl + S (contiguous)
  lambda_kern<<<dim3(128, 8), dim3(64), 0, stream>>>(qkv, cl, S);
  content_combine<<<dim3(16, 8, 16), dim3(256), 0, stream>>>(qkv, cl, S, rel, xbuf);
  gemm_mfma<256,1,true><<<dim3(256), dim3(512), 0, stream>>>(xbuf, wo, out_b, d_out);
}

// Round 9
// 413.735 us; speedup vs baseline: 1.0505x; 1.0505x over previous
//
#include <hip/hip_runtime.h>

// MHConvAttention MFMA v9b (resubmit #2 — R8 was an infra failure, never ran).
// B=16, C=256, H=W=64, NH=8, hd=32, WS=5.
// v9 changes vs v8 (434.6 us; combine 98.7 us, VALU 47%, floor ~16 us):
//  - ALGEBRAIC FOLD: out = Wo*(content + q.*pos) + b  ==>
//      out = q*Mb_b + (q.*pos)*Wo^T + b,
//    Mb_b[of][h*32+i] = sum_o' Wo[of][h*32+o'] * cl_bh[i][o'] * (0.1767/S).
//    * mb_kern (new, tiny): builds Mb (16 x 256x256 bf16) from cl,S,out_w.
//    * pos_combine: ex-content_combine minus cls staging + content loop;
//      writes qpos = q.*pos only.
//    * gemm_out: K=512 GEMM, A=[q(from qkv) ; qpos], B=[Mb_b ; Wo], f32 out.
//  - conv_mfma / gemm_mfma qkv / lambda unchanged.
//
// Workspace layout (bytes), total 136,986,624 (<= 137,101,312 known-good):
//   [0)           qkv bf16 (65536,768)  100,663,296   ALIASED with:
//   [0)           xpad bf16 (16,66,66,256) 35,684,352 (dead after conv)
//   [100663296)   x / qpos bf16 (65536,256) 33,554,432
//   [134217728)   cl f32 (128,32,32)        524,288
//   [134742016)   S  f32 (128,32)            16,384
//   [134758400)   wrb bf16 (9,256,256)    1,179,648 (dead after conv)   ALIASED:
//   [135938048)   wq  bf16 (768,256)        393,216 (dead after qkv gemm)
//   [134758400)   Mb  bf16 (16,256,256)   2,097,152 (written by mb_kern)
//   [136855552)   wo  bf16 (256,256)        131,072

typedef unsigned short u16;
typedef __bf16 bf16x8 __attribute__((ext_vector_type(8)));
typedef float f32x4 __attribute__((ext_vector_type(4)));
#define HW 4096

__device__ __forceinline__ float bf2f(u16 u){
  unsigned v = ((unsigned)u) << 16;
  return __builtin_bit_cast(float, v);
}
__device__ __forceinline__ u16 f2bf(float f){
  unsigned u = __builtin_bit_cast(unsigned, f);
  u = u + 0x7fffu + ((u >> 16) & 1u);   // RNE
  return (u16)(u >> 16);
}
__device__ __forceinline__ unsigned pack2(float a, float b){
  return (unsigned)f2bf(a) | ((unsigned)f2bf(b) << 16);
}
__device__ __forceinline__ void unpack2(unsigned u, float& a, float& b){
  a = bf2f((u16)(u & 0xffffu)); b = bf2f((u16)(u >> 16));
}
__device__ __forceinline__ void unp8(uint4 r, float* v){
  unpack2(r.x, v[0], v[1]); unpack2(r.y, v[2], v[3]);
  unpack2(r.z, v[4], v[5]); unpack2(r.w, v[6], v[7]);
}

__device__ __forceinline__ void gl2lds16(const u16* g, u16* l){
  __builtin_amdgcn_global_load_lds((__attribute__((address_space(1))) void*)g,
                                   (__attribute__((address_space(3))) void*)l, 16, 0, 0);
}

// ---------------- zero only the 1-px border of xpad ----------------
__global__ void zero_border(u16* __restrict__ xpad){
  int idx = blockIdx.x*256 + threadIdx.x;   // 133120 granules
  int g = idx & 31;
  int p = idx >> 5;                         // border px 0..4159
  int b = p / 260; int r = p - b*260;
  int y, x;
  if (r < 66)      { y = 0;      x = r; }
  else if (r < 132){ y = 65;     x = r-66; }
  else if (r < 196){ y = r-131;  x = 0; }
  else             { y = r-195;  x = 65; }
  *(uint4*)&xpad[((size_t)b*4356 + (size_t)y*66 + x)*256 + g*8] = uint4{0,0,0,0};
}

// ---------------- src NCHW f32 -> xpad NHWC bf16 (66x66, interior) ----------------
__global__ __launch_bounds__(256) void to_nhwc(const float* __restrict__ src,
                                               u16* __restrict__ xpad){
  __shared__ u16 sl[64*264];
  const int t = threadIdx.x, w = t>>6, lane = t&63;
  const int y = blockIdx.x, b = blockIdx.y;
  for (int cc = 0; cc < 64; ++cc){
    const int c = cc*4 + w;
    float v = src[((size_t)(b*256 + c))*HW + y*64 + lane];
    sl[lane*264 + c] = f2bf(v);
  }
  __syncthreads();
  #pragma unroll
  for (int i = 0; i < 8; ++i){
    int idx = t + 256*i;
    int p = idx >> 5, g = idx & 31;
    uint4 v = *(const uint4*)&sl[p*264 + g*8];
    *(uint4*)&xpad[((size_t)b*4356 + (size_t)(y+1)*66 + (p+1))*256 + g*8] = v;
  }
}

// ---------------- repack all weights to bf16 ----------------
__global__ void repack_w(const float* __restrict__ cpe_w, const float* __restrict__ qkv_w,
                         const float* __restrict__ out_w, u16* __restrict__ wrb,
                         u16* __restrict__ wq, u16* __restrict__ wo){
  int idx = blockIdx.x*256 + threadIdx.x;
  if (idx < 589824){
    int kk = idx >> 16, o = (idx >> 8) & 255, c = idx & 255;
    wrb[idx] = f2bf(cpe_w[((o*256 + c)*9) + kk]);
  } else if (idx < 786432){
    int j = idx - 589824;
    wq[j] = f2bf(qkv_w[j]);
  } else {
    int j = idx - 786432;
    wo[j] = f2bf(out_w[j]);
  }
}

// ---------------- CPE 3x3 conv: 256px x 256och tile, 8 waves, K=2304 ------------
__global__ __launch_bounds__(512, 2) void conv_mfma(const u16* __restrict__ xpad,
    const u16* __restrict__ wrb, const float* __restrict__ bias,
    u16* __restrict__ xout){
  __shared__ u16 As[32768];            // 2 x [256 px][64 k] = 2 x 32 KB
  __shared__ u16 Bs[32768];            // 2 x [256 o][64 k]
  const int t = threadIdx.x, w8 = t>>6, lane = t&63;
  const int idx = blockIdx.x;          // 0..255, 1 block/CU
  const int nb = (idx&7)*32 + (idx>>3);        // XCD-contiguous pixel blocks
  const int pg = nb*256;
  const int b = pg>>12, row0 = (pg&4095)>>6;   // 4 rows per block
  const size_t xb = (size_t)b*4356;
  const int dstb = w8*2048 + lane*8;   // u16 offset of issue-0 dest
  const u16* aP[4]; const u16* bP[4];
  #pragma unroll
  for (int i = 0; i < 4; ++i){
    int G = (w8*4+i)*64 + lane;
    int p = G>>3, gs = (G&7) ^ (p&7);
    aP[i] = xpad + (xb + (size_t)(row0 + (p>>6) + 1)*66 + (p&63) + 1)*256 + gs*8;
    bP[i] = wrb + (size_t)p*256 + gs*8;
  }
  const int wm = w8>>2, wn = w8&3;     // wave -> (px half, och quarter)
  const int qd = lane>>4;
  int a_off[8], b_off[4];
  #pragma unroll
  for (int m = 0; m < 8; ++m){
    int p = wm*128 + m*16 + (lane&15);
    a_off[m] = p*64 + ((qd ^ (p&7)) << 3);
  }
  #pragma unroll
  for (int n = 0; n < 4; ++n){
    int r = wn*64 + n*16 + (lane&15);
    b_off[n] = r*64 + ((qd ^ (r&7)) << 3);
  }
  f32x4 acc[8][4];
  #pragma unroll
  for (int i=0;i<8;++i)
    #pragma unroll
    for (int j=0;j<4;++j) acc[i][j] = f32x4{0.f,0.f,0.f,0.f};

  auto STAGE = [&](const int bufo, const int s){
    int c9 = s/9, tap = s - c9*9, ky = tap/3, kx = tap - ky*3;
    int offA = ((ky-1)*66 + (kx-1))*256 + c9*64;
    int offB = tap*65536 + c9*64;
    #pragma unroll
    for (int i = 0; i < 4; ++i){
      gl2lds16(aP[i] + offA, &As[bufo + dstb + i*512]);
      gl2lds16(bP[i] + offB, &Bs[bufo + dstb + i*512]);
    }
  };
  auto COMPUTE = [&](const int bufo){
    __builtin_amdgcn_s_setprio(1);
    #pragma unroll
    for (int kh = 0; kh < 2; ++kh){
      bf16x8 af[8], bfr[4];
      #pragma unroll
      for (int m = 0; m < 8; ++m)
        af[m] = __builtin_bit_cast(bf16x8, *(const uint4*)&As[bufo + (a_off[m] ^ (kh<<5))]);
      #pragma unroll
      for (int n = 0; n < 4; ++n)
        bfr[n] = __builtin_bit_cast(bf16x8, *(const uint4*)&Bs[bufo + (b_off[n] ^ (kh<<5))]);
      #pragma unroll
      for (int mt = 0; mt < 8; ++mt)
        #pragma unroll
        for (int nt = 0; nt < 4; ++nt)   // A=weights, B=pixels -> D[row=och][col=px]
          acc[mt][nt] = __builtin_amdgcn_mfma_f32_16x16x32_bf16(bfr[nt], af[mt], acc[mt][nt], 0,0,0);
    }
    __builtin_amdgcn_s_setprio(0);
  };
  #define SYNC asm volatile("s_waitcnt vmcnt(0)" ::: "memory"); __builtin_amdgcn_s_barrier();

  STAGE(0, 0);
  SYNC
  for (int s2 = 0; s2 < 18; ++s2){       // 36 K-steps, x2 unrolled (literal bufo)
    STAGE(16384, 2*s2+1);
    COMPUTE(0);
    SYNC
    if (s2 < 17) STAGE(0, 2*s2+2);
    COMPUTE(16384);
    SYNC
  }
  #pragma unroll
  for (int nt = 0; nt < 4; ++nt){
    const int och4 = wn*64 + nt*16 + qd*4;
    float4 b4 = *(const float4*)&bias[och4];
    #pragma unroll
    for (int mt = 0; mt < 8; ++mt){
      const int px = wm*128 + mt*16 + (lane&15);
      const int y = row0 + (px>>6), x = px&63;
      ushort4 r4 = *(const ushort4*)&xpad[(xb + (size_t)(y+1)*66 + x + 1)*256 + och4];
      ushort4 s;
      s.x = f2bf(acc[mt][nt][0] + b4.x + bf2f(r4.x));
      s.y = f2bf(acc[mt][nt][1] + b4.y + bf2f(r4.y));
      s.z = f2bf(acc[mt][nt][2] + b4.z + bf2f(r4.z));
      s.w = f2bf(acc[mt][nt][3] + b4.w + bf2f(r4.w));
      *(ushort4*)&xout[(size_t)(pg + px)*256 + och4] = s;
    }
  }
  #undef SYNC
}

// ---------------- K=256 MFMA GEMM (qkv projection), 256x256 tile, 8 waves. -----
template<int NO, int NOT>
__global__ __launch_bounds__(512, 2) void gemm_mfma(const u16* __restrict__ act,
    const u16* __restrict__ wt, void* __restrict__ out){
  __shared__ u16 As[32768];
  __shared__ u16 Bs[32768];
  const int t = threadIdx.x, w8 = t>>6, lane = t&63;
  const int idx = blockIdx.x;
  const int x8 = idx&7, q = idx>>3;
  const int ot = q % NOT, nb = x8*32 + q / NOT;
  const int pg = nb*256, o0 = ot*256;
  const int dstb = w8*2048 + lane*8;
  const u16* aP[4]; const u16* bP[4];
  #pragma unroll
  for (int i = 0; i < 4; ++i){
    int G = (w8*4+i)*64 + lane;
    int p = G>>3, gs = (G&7) ^ (p&7);
    aP[i] = act + (size_t)(pg + p)*256 + gs*8;
    bP[i] = wt  + (size_t)(o0 + p)*256 + gs*8;
  }
  const int wm = w8>>2, wn = w8&3;
  const int qd = lane>>4;
  int a_off[8], b_off[4];
  #pragma unroll
  for (int m = 0; m < 8; ++m){
    int p = wm*128 + m*16 + (lane&15);
    a_off[m] = p*64 + ((qd ^ (p&7)) << 3);
  }
  #pragma unroll
  for (int n = 0; n < 4; ++n){
    int r = wn*64 + n*16 + (lane&15);
    b_off[n] = r*64 + ((qd ^ (r&7)) << 3);
  }
  f32x4 acc[8][4];
  #pragma unroll
  for (int i=0;i<8;++i)
    #pragma unroll
    for (int j=0;j<4;++j) acc[i][j] = f32x4{0.f,0.f,0.f,0.f};

  auto STAGE = [&](const int bufo, const int s){
    const int c0 = s*64;
    #pragma unroll
    for (int i = 0; i < 4; ++i){
      gl2lds16(aP[i] + c0, &As[bufo + dstb + i*512]);
      gl2lds16(bP[i] + c0, &Bs[bufo + dstb + i*512]);
    }
  };
  auto COMPUTE = [&](const int bufo){
    __builtin_amdgcn_s_setprio(1);
    #pragma unroll
    for (int kh = 0; kh < 2; ++kh){
      bf16x8 af[8], bfr[4];
      #pragma unroll
      for (int m = 0; m < 8; ++m)
        af[m] = __builtin_bit_cast(bf16x8, *(const uint4*)&As[bufo + (a_off[m] ^ (kh<<5))]);
      #pragma unroll
      for (int n = 0; n < 4; ++n)
        bfr[n] = __builtin_bit_cast(bf16x8, *(const uint4*)&Bs[bufo + (b_off[n] ^ (kh<<5))]);
      #pragma unroll
      for (int mt = 0; mt < 8; ++mt)
        #pragma unroll
        for (int nt = 0; nt < 4; ++nt)
          acc[mt][nt] = __builtin_amdgcn_mfma_f32_16x16x32_bf16(bfr[nt], af[mt], acc[mt][nt], 0,0,0);
    }
    __builtin_amdgcn_s_setprio(0);
  };
  #define SYNC asm volatile("s_waitcnt vmcnt(0)" ::: "memory"); __builtin_amdgcn_s_barrier();

  STAGE(0, 0);
  SYNC
  for (int s2 = 0; s2 < 2; ++s2){        // 4 K-steps
    STAGE(16384, 2*s2+1);
    COMPUTE(0);
    SYNC
    if (s2 < 1) STAGE(0, 2*s2+2);
    COMPUTE(16384);
    SYNC
  }
  u16* op = (u16*)out;
  #pragma unroll
  for (int nt = 0; nt < 4; ++nt){
    const int och4 = o0 + wn*64 + nt*16 + qd*4;
    #pragma unroll
    for (int mt = 0; mt < 8; ++mt){
      const int px = wm*128 + mt*16 + (lane&15);
      ushort4 s;
      s.x = f2bf(acc[mt][nt][0]); s.y = f2bf(acc[mt][nt][1]);
      s.z = f2bf(acc[mt][nt][2]); s.w = f2bf(acc[mt][nt][3]);
      *(ushort4*)&op[(size_t)(pg + px)*NO + och4] = s;
    }
  }
  #undef SYNC
}

// ---------------- final GEMM: out = [q ; qpos] x [Mb_b ; Wo] + bias, K=512 -----
__global__ __launch_bounds__(512, 2) void gemm_out(const u16* __restrict__ qkv,
    const u16* __restrict__ qpos, const u16* __restrict__ Mb,
    const u16* __restrict__ wo, const float* __restrict__ bias,
    float* __restrict__ out){
  __shared__ u16 As[32768];
  __shared__ u16 Bs[32768];
  const int t = threadIdx.x, w8 = t>>6, lane = t&63;
  const int idx = blockIdx.x;
  const int nb = (idx&7)*32 + (idx>>3);
  const int pg = nb*256;
  const int b = pg>>12, hw0 = pg&4095;
  const int dstb = w8*2048 + lane*8;
  const u16 *aQ[4], *aX[4], *bM[4], *bW[4];
  #pragma unroll
  for (int i = 0; i < 4; ++i){
    int G = (w8*4+i)*64 + lane;
    int p = G>>3, gs = (G&7) ^ (p&7);
    aQ[i] = qkv  + (size_t)(pg + p)*768 + gs*8;          // q slice, row stride 768
    aX[i] = qpos + (size_t)(pg + p)*256 + gs*8;
    bM[i] = Mb   + ((size_t)b*256 + p)*256 + gs*8;       // per-batch Mb
    bW[i] = wo   + (size_t)p*256 + gs*8;
  }
  const int wm = w8>>2, wn = w8&3;
  const int qd = lane>>4;
  int a_off[8], b_off[4];
  #pragma unroll
  for (int m = 0; m < 8; ++m){
    int p = wm*128 + m*16 + (lane&15);
    a_off[m] = p*64 + ((qd ^ (p&7)) << 3);
  }
  #pragma unroll
  for (int n = 0; n < 4; ++n){
    int r = wn*64 + n*16 + (lane&15);
    b_off[n] = r*64 + ((qd ^ (r&7)) << 3);
  }
  f32x4 acc[8][4];
  #pragma unroll
  for (int i=0;i<8;++i)
    #pragma unroll
    for (int j=0;j<4;++j) acc[i][j] = f32x4{0.f,0.f,0.f,0.f};

  auto STAGE = [&](const int bufo, const int s){
    #pragma unroll
    for (int i = 0; i < 4; ++i){
      const u16* sa = (s < 4) ? (aQ[i] + s*64)      : (aX[i] + (s-4)*64);
      const u16* sb = (s < 4) ? (bM[i] + s*64)      : (bW[i] + (s-4)*64);
      gl2lds16(sa, &As[bufo + dstb + i*512]);
      gl2lds16(sb, &Bs[bufo + dstb + i*512]);
    }
  };
  auto COMPUTE = [&](const int bufo){
    __builtin_amdgcn_s_setprio(1);
    #pragma unroll
    for (int kh = 0; kh < 2; ++kh){
      bf16x8 af[8], bfr[4];
      #pragma unroll
      for (int m = 0; m < 8; ++m)
        af[m] = __builtin_bit_cast(bf16x8, *(const uint4*)&As[bufo + (a_off[m] ^ (kh<<5))]);
      #pragma unroll
      for (int n = 0; n < 4; ++n)
        bfr[n] = __builtin_bit_cast(bf16x8, *(const uint4*)&Bs[bufo + (b_off[n] ^ (kh<<5))]);
      #pragma unroll
      for (int mt = 0; mt < 8; ++mt)
        #pragma unroll
        for (int nt = 0; nt < 4; ++nt)
          acc[mt][nt] = __builtin_amdgcn_mfma_f32_16x16x32_bf16(af[mt], bfr[nt], acc[mt][nt], 0,0,0);
    }
    __builtin_amdgcn_s_setprio(0);
  };
  #define SYNC asm volatile("s_waitcnt vmcnt(0)" ::: "memory"); __builtin_amdgcn_s_barrier();

  STAGE(0, 0);
  SYNC
  #pragma unroll
  for (int s2 = 0; s2 < 4; ++s2){        // 8 K-steps (K=512)
    STAGE(16384, 2*s2+1);
    COMPUTE(0);
    SYNC
    if (s2 < 3) STAGE(0, 2*s2+2);
    COMPUTE(16384);
    SYNC
  }
  const int col = lane&15, row_l = qd*4;
  #pragma unroll
  for (int nt = 0; nt < 4; ++nt){
    const int och = wn*64 + nt*16 + col;
    const float bo2 = bias[och];
    #pragma unroll
    for (int mt = 0; mt < 8; ++mt){
      const int pl = wm*128 + mt*16 + row_l;
      float4 v;
      v.x = acc[mt][nt][0]+bo2; v.y = acc[mt][nt][1]+bo2;
      v.z = acc[mt][nt][2]+bo2; v.w = acc[mt][nt][3]+bo2;
      *(float4*)&out[((size_t)b*256 + och)*HW + hw0 + pl] = v;
    }
  }
  #undef SYNC
}

__global__ void zero_cl(float* __restrict__ cl){
  cl[blockIdx.x*256 + threadIdx.x] = 0.f;   // zeros cl (131072) + S (4096)
}

// ---------------- lambda: cl'[b',i,o] = sum_n exp(k[n][i])*v[n][o]; S[b',i] = sum_n exp ----
__global__ __launch_bounds__(64) void lambda_kern(const u16* __restrict__ qkv,
                                                  float* __restrict__ cl,
                                                  float* __restrict__ S){
  __shared__ float Kl[64*36];
  __shared__ float Vl[64*36];
  const int t = threadIdx.x;
  const int bp = blockIdx.x, split = blockIdx.y;
  const int b = bp>>3, h = bp&7;
  const int ig = t&7, og = t>>3;
  float acc[4][4];
  float sacc[4] = {0.f,0.f,0.f,0.f};
  #pragma unroll
  for (int i=0;i<4;++i)
    #pragma unroll
    for (int j=0;j<4;++j) acc[i][j] = 0.f;
  for (int chunk = 0; chunk < 8; ++chunk){
    const int n = split*512 + chunk*64 + t;
    const u16* kp = qkv + (size_t)(b*HW + n)*768 + 256 + h*32;   // raw k
    const u16* vp = kp + 256;
    uint4 k4[4], v4[4];
    #pragma unroll
    for (int qq=0;qq<4;++qq){ k4[qq] = ((const uint4*)kp)[qq]; v4[qq] = ((const uint4*)vp)[qq]; }
    __syncthreads();
    #pragma unroll
    for (int qq=0;qq<4;++qq){
      float kv[8], vv[8]; unp8(k4[qq], kv); unp8(v4[qq], vv);
      #pragma unroll
      for (int e=0;e<8;++e) kv[e] = __expf(kv[e]);
      *(float4*)&Kl[t*36 + qq*8]     = float4{kv[0],kv[1],kv[2],kv[3]};
      *(float4*)&Kl[t*36 + qq*8 + 4] = float4{kv[4],kv[5],kv[6],kv[7]};
      *(float4*)&Vl[t*36 + qq*8]     = float4{vv[0],vv[1],vv[2],vv[3]};
      *(float4*)&Vl[t*36 + qq*8 + 4] = float4{vv[4],vv[5],vv[6],vv[7]};
    }
    __syncthreads();
    for (int p = 0; p < 64; ++p){
      float4 kf = *(const float4*)&Kl[p*36 + ig*4];
      float4 vf = *(const float4*)&Vl[p*36 + og*4];
      float kfa[4] = {kf.x,kf.y,kf.z,kf.w};
      float vfa[4] = {vf.x,vf.y,vf.z,vf.w};
      #pragma unroll
      for (int i=0;i<4;++i){
        sacc[i] += kfa[i];
        #pragma unroll
        for (int j=0;j<4;++j) acc[i][j] = fmaf(kfa[i], vfa[j], acc[i][j]);
      }
    }
  }
  #pragma unroll
  for (int i=0;i<4;++i)
    #pragma unroll
    for (int j=0;j<4;++j)
      atomicAdd(&cl[(size_t)bp*1024 + (ig*4+i)*32 + og*4+j], acc[i][j]);
  if (og == 0){
    #pragma unroll
    for (int i=0;i<4;++i) atomicAdd(&S[bp*32 + ig*4 + i], sacc[i]);
  }
}

// ---------------- Mb_b[of][h*32+i] = sum_o' wo[of][h*32+o'] * cl_bh[i][o'] / S --
__global__ __launch_bounds__(256) void mb_kern(const float* __restrict__ cl,
    const float* __restrict__ S, const float* __restrict__ out_w,
    u16* __restrict__ Mb){
  __shared__ float clS[1024];
  __shared__ float sinv[32];
  const int t = threadIdx.x;
  const int h = blockIdx.x & 7, b = blockIdx.x >> 3;
  const int bp = b*8 + h;
  for (int idx = t; idx < 1024; idx += 256)
    clS[idx] = cl[(size_t)bp*1024 + idx];
  if (t < 32) sinv[t] = 0.17677669529663687f / S[bp*32 + t];
  __syncthreads();
  float wrow[32];
  #pragma unroll
  for (int o = 0; o < 32; ++o) wrow[o] = out_w[t*256 + h*32 + o];
  u16 out16[32];
  #pragma unroll
  for (int i = 0; i < 32; ++i){
    float a = 0.f;
    #pragma unroll
    for (int o = 0; o < 32; ++o) a = fmaf(wrow[o], clS[i*32+o], a);
    out16[i] = f2bf(a * sinv[i]);
  }
  u16* mp = Mb + ((size_t)b*256 + t)*256 + h*32;
  #pragma unroll
  for (int g = 0; g < 4; ++g)
    ((uint4*)mp)[g] = *(uint4*)&out16[g*8];
}

// ---------------- depthwise-5x5 pos-lambda; writes qpos = q .* pos ----------------
// vt layout: [chg 0..3][hp 0..399][8 u16] -> granule idx = chg*400 + hp.
__global__ __launch_bounds__(256) void pos_combine(const u16* __restrict__ qkv,
    const float* __restrict__ rel, u16* __restrict__ res){
  __shared__ u16 vt[12800];
  __shared__ float relT[800];
  const int t = threadIdx.x;
  const int tile = blockIdx.x, h = blockIdx.y, b = blockIdx.z;
  const int x0 = (tile&3)*16, y0 = (tile>>2)*16;
  for (int idx = t; idx < 800; idx += 256){
    int tap = idx>>5, ch = idx&31;
    relT[idx] = rel[ch*25 + tap];
  }
  #pragma unroll
  for (int i = 0; i < 7; ++i){
    int idx = t + 256*i;
    if (idx < 1600){
      int hp = idx>>2, g = idx&3;
      int hy = hp/20, hx = hp - hy*20;
      int y = y0 + hy - 2, x = x0 + hx - 2;
      uint4 v = uint4{0,0,0,0};
      if ((unsigned)y < 64u && (unsigned)x < 64u)
        v = *(const uint4*)&qkv[(size_t)(b*HW + y*64 + x)*768 + 512 + h*32 + g*8];
      *(uint4*)&vt[(g*400 + hp)*8] = v;
    }
  }
  __syncthreads();
  const int py = t>>4, px = t&15;
  const int pix = b*HW + (y0+py)*64 + x0 + px;
  const u16* qp = qkv + (size_t)pix*768 + h*32;
  float qv[32];
  {
    uint4 q0 = ((const uint4*)qp)[0], q1 = ((const uint4*)qp)[1];
    uint4 q2 = ((const uint4*)qp)[2], q3 = ((const uint4*)qp)[3];
    unp8(q0, qv); unp8(q1, qv+8); unp8(q2, qv+16); unp8(q3, qv+24);
  }
  float outv[32];
  #pragma unroll
  for (int chg = 0; chg < 4; ++chg){
    float pos[8];
    #pragma unroll
    for (int j=0;j<8;++j) pos[j] = 0.f;
    #pragma unroll
    for (int dy = 0; dy < 5; ++dy)
      #pragma unroll
      for (int dx = 0; dx < 5; ++dx){
        int hp = (py+dy)*20 + px + dx;
        uint4 v4 = *(const uint4*)&vt[(chg*400 + hp)*8];
        float vv[8]; unp8(v4, vv);
        float4 r0 = *(const float4*)&relT[(dy*5+dx)*32 + chg*8];
        float4 r1 = *(const float4*)&relT[(dy*5+dx)*32 + chg*8 + 4];
        pos[0]=fmaf(r0.x, vv[0], pos[0]); pos[1]=fmaf(r0.y, vv[1], pos[1]);
        pos[2]=fmaf(r0.z, vv[2], pos[2]); pos[3]=fmaf(r0.w, vv[3], pos[3]);
        pos[4]=fmaf(r1.x, vv[4], pos[4]); pos[5]=fmaf(r1.y, vv[5], pos[5]);
        pos[6]=fmaf(r1.z, vv[6], pos[6]); pos[7]=fmaf(r1.w, vv[7], pos[7]);
      }
    #pragma unroll
    for (int j=0;j<8;++j) outv[chg*8+j] = qv[chg*8+j] * pos[j];
  }
  u16* rp = res + (size_t)pix*256 + h*32;
  #pragma unroll
  for (int g = 0; g < 4; ++g){
    uint4 o_;
    o_.x = pack2(outv[g*8+0], outv[g*8+1]);
    o_.y = pack2(outv[g*8+2], outv[g*8+3]);
    o_.z = pack2(outv[g*8+4], outv[g*8+5]);
    o_.w = pack2(outv[g*8+6], outv[g*8+7]);
    ((uint4*)rp)[g] = o_;
  }
}

extern "C" void kernel_launch(void* const* d_in, const int* in_sizes, int n_in,
                              void* d_out, int out_size, void* d_ws, size_t ws_size,
                              hipStream_t stream) {
  const float* src   = (const float*)d_in[0];
  const float* rel   = (const float*)d_in[1];
  const float* qkv_w = (const float*)d_in[2];
  const float* cpe_w = (const float*)d_in[3];
  const float* cpe_b = (const float*)d_in[4];
  const float* out_w = (const float*)d_in[5];
  const float* out_b = (const float*)d_in[6];
  char* ws = (char*)d_ws;
  u16*   qkv  = (u16*)(ws);
  u16*   xpad = (u16*)(ws);                    // aliased (dead after conv)
  u16*   xbuf = (u16*)(ws + 100663296);        // x, then qpos
  float* cl   = (float*)(ws + 134217728);
  float* S    = (float*)(ws + 134742016);
  u16*   wrb  = (u16*)(ws + 134758400);        // dead after conv
  u16*   wq   = (u16*)(ws + 135938048);        // dead after qkv gemm
  u16*   Mb   = (u16*)(ws + 134758400);        // aliases wrb+wq (written later)
  u16*   wo   = (u16*)(ws + 136855552);

  zero_border<<<dim3(520), dim3(256), 0, stream>>>(xpad);
  to_nhwc<<<dim3(64, 16), dim3(256), 0, stream>>>(src, xpad);
  repack_w<<<dim3(3328), dim3(256), 0, stream>>>(cpe_w, qkv_w, out_w, wrb, wq, wo);
  conv_mfma<<<dim3(256), dim3(512), 0, stream>>>(xpad, wrb, cpe_b, xbuf);
  gemm_mfma<768,3><<<dim3(768), dim3(512), 0, stream>>>(xbuf, wq, (void*)qkv);
  zero_cl<<<dim3(528), dim3(256), 0, stream>>>(cl);   // zeros cl + S (contiguous)
  lambda_kern<<<dim3(128, 8), dim3(64), 0, stream>>>(qkv, cl, S);
  mb_kern<<<dim3(128), dim3(256), 0, stream>>>(cl, S, out_w, Mb);
  pos_combine<<<dim3(16, 8, 16), dim3(256), 0, stream>>>(qkv, rel, xbuf);
  gemm_out<<<dim3(256), dim3(512), 0, stream>>>(qkv, xbuf, Mb, wo, out_b, (float*)d_out);
}

// Round 11
// 412.862 us; speedup vs baseline: 1.0527x; 1.0021x over previous
//
#include <hip/hip_runtime.h>

// MHConvAttention MFMA v10 (resubmit — R10 was GPUAcquisitionTimeout, never ran).
// B=16, C=256, H=W=64, NH=8, hd=32, WS=5.
// v10 changes vs v9b (413.7 us; conv 95 us @ MfmaUtil 33%, VALU 14%):
//  - conv_mfma: A-HALO restructure. The 9 taps are shifted windows of one
//    6-row halo [396 hp][64 ch] (50.7 KB), staged ONCE per c9 (4x/kernel)
//    instead of re-staged per tap (9x). Per-K-step staging halves to B-only
//    (32 KB). B double-buffered with 2-barrier counted-vmcnt pattern (T4):
//    COMPUTE; barrier; STAGE_B(s+2); vmcnt(4); barrier — loads stay in
//    flight across barriers, never vmcnt(0) in steady state.
//  - everything else unchanged from v9b (algebraic fold, m248 gemms).
//
// Workspace layout (bytes), total 136,986,624 (<= 137,101,312 known-good):
//   [0)           qkv bf16 (65536,768)  100,663,296   ALIASED with:
//   [0)           xpad bf16 (16,66,66,256) 35,684,352 (dead after conv)
//   [100663296)   x / qpos bf16 (65536,256) 33,554,432
//   [134217728)   cl f32 (128,32,32)        524,288
//   [134742016)   S  f32 (128,32)            16,384
//   [134758400)   wrb bf16 (9,256,256)    1,179,648 (dead after conv)   ALIASED:
//   [135938048)   wq  bf16 (768,256)        393,216 (dead after qkv gemm)
//   [134758400)   Mb  bf16 (16,256,256)   2,097,152 (written by mb_kern)
//   [136855552)   wo  bf16 (256,256)        131,072

typedef unsigned short u16;
typedef __bf16 bf16x8 __attribute__((ext_vector_type(8)));
typedef float f32x4 __attribute__((ext_vector_type(4)));
#define HW 4096

__device__ __forceinline__ float bf2f(u16 u){
  unsigned v = ((unsigned)u) << 16;
  return __builtin_bit_cast(float, v);
}
__device__ __forceinline__ u16 f2bf(float f){
  unsigned u = __builtin_bit_cast(unsigned, f);
  u = u + 0x7fffu + ((u >> 16) & 1u);   // RNE
  return (u16)(u >> 16);
}
__device__ __forceinline__ unsigned pack2(float a, float b){
  return (unsigned)f2bf(a) | ((unsigned)f2bf(b) << 16);
}
__device__ __forceinline__ void unpack2(unsigned u, float& a, float& b){
  a = bf2f((u16)(u & 0xffffu)); b = bf2f((u16)(u >> 16));
}
__device__ __forceinline__ void unp8(uint4 r, float* v){
  unpack2(r.x, v[0], v[1]); unpack2(r.y, v[2], v[3]);
  unpack2(r.z, v[4], v[5]); unpack2(r.w, v[6], v[7]);
}

__device__ __forceinline__ void gl2lds16(const u16* g, u16* l){
  __builtin_amdgcn_global_load_lds((__attribute__((address_space(1))) void*)g,
                                   (__attribute__((address_space(3))) void*)l, 16, 0, 0);
}

// ---------------- zero only the 1-px border of xpad ----------------
__global__ void zero_border(u16* __restrict__ xpad){
  int idx = blockIdx.x*256 + threadIdx.x;   // 133120 granules
  int g = idx & 31;
  int p = idx >> 5;                         // border px 0..4159
  int b = p / 260; int r = p - b*260;
  int y, x;
  if (r < 66)      { y = 0;      x = r; }
  else if (r < 132){ y = 65;     x = r-66; }
  else if (r < 196){ y = r-131;  x = 0; }
  else             { y = r-195;  x = 65; }
  *(uint4*)&xpad[((size_t)b*4356 + (size_t)y*66 + x)*256 + g*8] = uint4{0,0,0,0};
}

// ---------------- src NCHW f32 -> xpad NHWC bf16 (66x66, interior) ----------------
__global__ __launch_bounds__(256) void to_nhwc(const float* __restrict__ src,
                                               u16* __restrict__ xpad){
  __shared__ u16 sl[64*264];
  const int t = threadIdx.x, w = t>>6, lane = t&63;
  const int y = blockIdx.x, b = blockIdx.y;
  for (int cc = 0; cc < 64; ++cc){
    const int c = cc*4 + w;
    float v = src[((size_t)(b*256 + c))*HW + y*64 + lane];
    sl[lane*264 + c] = f2bf(v);
  }
  __syncthreads();
  #pragma unroll
  for (int i = 0; i < 8; ++i){
    int idx = t + 256*i;
    int p = idx >> 5, g = idx & 31;
    uint4 v = *(const uint4*)&sl[p*264 + g*8];
    *(uint4*)&xpad[((size_t)b*4356 + (size_t)(y+1)*66 + (p+1))*256 + g*8] = v;
  }
}

// ---------------- repack all weights to bf16 ----------------
__global__ void repack_w(const float* __restrict__ cpe_w, const float* __restrict__ qkv_w,
                         const float* __restrict__ out_w, u16* __restrict__ wrb,
                         u16* __restrict__ wq, u16* __restrict__ wo){
  int idx = blockIdx.x*256 + threadIdx.x;
  if (idx < 589824){
    int kk = idx >> 16, o = (idx >> 8) & 255, c = idx & 255;
    wrb[idx] = f2bf(cpe_w[((o*256 + c)*9) + kk]);
  } else if (idx < 786432){
    int j = idx - 589824;
    wq[j] = f2bf(qkv_w[j]);
  } else {
    int j = idx - 786432;
    wo[j] = f2bf(out_w[j]);
  }
}

// ---------------- CPE 3x3 conv: 256px x 256och tile, 8 waves, A-halo ------------
// Ah: [396 hp][64 ch], hp = hr*66+hx covers rows row0..row0+5, cols 0..65.
// Granule slot g at row hp holds logical granule g^(hp&7) (pre-swizzled src).
// Taps read Ah at hp = hbase + ky*66 + kx (shifted windows, no re-stage).
// Bs: 2 x [256 och][64 ch] double-buffered, counted-vmcnt prefetch depth 2.
__global__ __launch_bounds__(512, 2) void conv_mfma(const u16* __restrict__ xpad,
    const u16* __restrict__ wrb, const float* __restrict__ bias,
    u16* __restrict__ xout){
  __shared__ u16 Ah[25344];            // 50.7 KB halo, restaged 4x (per c9)
  __shared__ u16 Bs[32768];            // 2 x 32 KB weight dbuf
  const int t = threadIdx.x, w8 = t>>6, lane = t&63;
  const int idx = blockIdx.x;          // 0..255, 1 block/CU
  const int nb = (idx&7)*32 + (idx>>3);        // XCD-contiguous pixel blocks
  const int pg = nb*256;
  const int b = pg>>12, row0 = (pg&4095)>>6;   // 4 output rows per block
  const size_t xb = (size_t)b*4356;
  // A-halo staging: granule G -> hp=G>>3, slot G&7 holds logical (G&7)^(hp&7)
  const u16* aHp[6]; const u16* aHt; const u16* bPn[4];
  #pragma unroll
  for (int i = 0; i < 6; ++i){
    int G = i*512 + t, hp = G>>3, gs = (G&7) ^ (hp&7);
    int hr = hp/66, hx = hp - hr*66;
    aHp[i] = xpad + (xb + (size_t)(row0+hr)*66 + hx)*256 + gs*8;
  }
  {
    int G = 3072 + t, hp = G>>3, gs = (G&7) ^ (hp&7);
    int hr = hp/66, hx = hp - hr*66;
    aHt = xpad + (xb + (size_t)(row0+hr)*66 + hx)*256 + gs*8;
  }
  #pragma unroll
  for (int i = 0; i < 4; ++i){
    int G = i*512 + t, o = G>>3, gs = (G&7) ^ (o&7);
    bPn[i] = wrb + (size_t)o*256 + gs*8;
  }
  const int wm = w8>>2, wn = w8&3;     // wave -> (px half, och quarter)
  const int qd = lane>>4;
  int hbase[8], b_off[4];
  #pragma unroll
  for (int m = 0; m < 8; ++m){
    int p = wm*128 + m*16 + (lane&15);
    hbase[m] = (p>>6)*66 + (p&63);
  }
  #pragma unroll
  for (int n = 0; n < 4; ++n){
    int r = wn*64 + n*16 + (lane&15);
    b_off[n] = r*64 + ((qd ^ (r&7)) << 3);
  }
  f32x4 acc[8][4];
  #pragma unroll
  for (int i=0;i<8;++i)
    #pragma unroll
    for (int j=0;j<4;++j) acc[i][j] = f32x4{0.f,0.f,0.f,0.f};

  auto STAGE_A = [&](const int c9o){   // c9o = c9*64 (u16 channel offset)
    #pragma unroll
    for (int i = 0; i < 6; ++i)
      gl2lds16(aHp[i] + c9o, &Ah[(i*512 + t)*8]);
    if (t < 96) gl2lds16(aHt + c9o, &Ah[(3072 + t)*8]);
  };
  auto STAGE_B = [&](const int bufo, const int s){
    const int c9 = s/9, tap = s - c9*9;
    const int soff = tap*65536 + c9*64;
    #pragma unroll
    for (int i = 0; i < 4; ++i)
      gl2lds16(bPn[i] + soff, &Bs[bufo + (i*512 + t)*8]);
  };
  auto COMPUTE = [&](const int kyx, const int bufo){
    __builtin_amdgcn_s_setprio(1);
    int aoff[8];
    #pragma unroll
    for (int m = 0; m < 8; ++m){
      int hp = hbase[m] + kyx;
      aoff[m] = hp*64 + ((qd ^ (hp&7)) << 3);
    }
    #pragma unroll
    for (int kh = 0; kh < 2; ++kh){
      bf16x8 af[8], bfr[4];
      #pragma unroll
      for (int m = 0; m < 8; ++m)
        af[m] = __builtin_bit_cast(bf16x8, *(const uint4*)&Ah[aoff[m] ^ (kh<<5)]);
      #pragma unroll
      for (int n = 0; n < 4; ++n)
        bfr[n] = __builtin_bit_cast(bf16x8, *(const uint4*)&Bs[bufo + (b_off[n] ^ (kh<<5))]);
      #pragma unroll
      for (int mt = 0; mt < 8; ++mt)
        #pragma unroll
        for (int nt = 0; nt < 4; ++nt)   // A=weights(B-op), B=pixels -> D[och][px]
          acc[mt][nt] = __builtin_amdgcn_mfma_f32_16x16x32_bf16(bfr[nt], af[mt], acc[mt][nt], 0,0,0);
    }
    __builtin_amdgcn_s_setprio(0);
  };

  // prologue: A-halo(c9=0) + B stages 0,1; wait A+B0 (leave B1 in flight)
  STAGE_A(0);
  STAGE_B(0, 0);
  STAGE_B(16384, 1);
  asm volatile("s_waitcnt vmcnt(4)" ::: "memory");
  __builtin_amdgcn_s_barrier();
  for (int s = 0; s < 36; ++s){
    const int c9 = s/9, tap = s - c9*9;
    const int kyx = (tap/3)*66 + (tap - (tap/3)*3);
    COMPUTE(kyx, (s&1)*16384);
    if (s == 35) break;
    asm volatile("s_barrier" ::: "memory");      // frees Bs[s&1] (and Ah at c9 end)
    if (tap == 8) STAGE_A((c9+1)*64);            // boundary: restage halo (before B!)
    if (s <= 33) STAGE_B((s&1)*16384, s+2);      // prefetch depth 2
    if (s == 34) { asm volatile("s_waitcnt vmcnt(0)" ::: "memory"); }
    else         { asm volatile("s_waitcnt vmcnt(4)" ::: "memory"); }  // counted: B(s+2) stays in flight
    __builtin_amdgcn_s_barrier();                // publish stage s+1 (+ halo)
  }
  // epilogue: lane holds 4 consecutive och at one px -> 8-B stores
  #pragma unroll
  for (int nt = 0; nt < 4; ++nt){
    const int och4 = wn*64 + nt*16 + qd*4;
    float4 b4 = *(const float4*)&bias[och4];
    #pragma unroll
    for (int mt = 0; mt < 8; ++mt){
      const int px = wm*128 + mt*16 + (lane&15);
      const int y = row0 + (px>>6), x = px&63;
      ushort4 r4 = *(const ushort4*)&xpad[(xb + (size_t)(y+1)*66 + x + 1)*256 + och4];
      ushort4 s;
      s.x = f2bf(acc[mt][nt][0] + b4.x + bf2f(r4.x));
      s.y = f2bf(acc[mt][nt][1] + b4.y + bf2f(r4.y));
      s.z = f2bf(acc[mt][nt][2] + b4.z + bf2f(r4.z));
      s.w = f2bf(acc[mt][nt][3] + b4.w + bf2f(r4.w));
      *(ushort4*)&xout[(size_t)(pg + px)*256 + och4] = s;
    }
  }
}

// ---------------- K=256 MFMA GEMM (qkv projection), 256x256 tile, 8 waves. -----
template<int NO, int NOT>
__global__ __launch_bounds__(512, 2) void gemm_mfma(const u16* __restrict__ act,
    const u16* __restrict__ wt, void* __restrict__ out){
  __shared__ u16 As[32768];
  __shared__ u16 Bs[32768];
  const int t = threadIdx.x, w8 = t>>6, lane = t&63;
  const int idx = blockIdx.x;
  const int x8 = idx&7, q = idx>>3;
  const int ot = q % NOT, nb = x8*32 + q / NOT;
  const int pg = nb*256, o0 = ot*256;
  const int dstb = w8*2048 + lane*8;
  const u16* aP[4]; const u16* bP[4];
  #pragma unroll
  for (int i = 0; i < 4; ++i){
    int G = (w8*4+i)*64 + lane;
    int p = G>>3, gs = (G&7) ^ (p&7);
    aP[i] = act + (size_t)(pg + p)*256 + gs*8;
    bP[i] = wt  + (size_t)(o0 + p)*256 + gs*8;
  }
  const int wm = w8>>2, wn = w8&3;
  const int qd = lane>>4;
  int a_off[8], b_off[4];
  #pragma unroll
  for (int m = 0; m < 8; ++m){
    int p = wm*128 + m*16 + (lane&15);
    a_off[m] = p*64 + ((qd ^ (p&7)) << 3);
  }
  #pragma unroll
  for (int n = 0; n < 4; ++n){
    int r = wn*64 + n*16 + (lane&15);
    b_off[n] = r*64 + ((qd ^ (r&7)) << 3);
  }
  f32x4 acc[8][4];
  #pragma unroll
  for (int i=0;i<8;++i)
    #pragma unroll
    for (int j=0;j<4;++j) acc[i][j] = f32x4{0.f,0.f,0.f,0.f};

  auto STAGE = [&](const int bufo, const int s){
    const int c0 = s*64;
    #pragma unroll
    for (int i = 0; i < 4; ++i){
      gl2lds16(aP[i] + c0, &As[bufo + dstb + i*512]);
      gl2lds16(bP[i] + c0, &Bs[bufo + dstb + i*512]);
    }
  };
  auto COMPUTE = [&](const int bufo){
    __builtin_amdgcn_s_setprio(1);
    #pragma unroll
    for (int kh = 0; kh < 2; ++kh){
      bf16x8 af[8], bfr[4];
      #pragma unroll
      for (int m = 0; m < 8; ++m)
        af[m] = __builtin_bit_cast(bf16x8, *(const uint4*)&As[bufo + (a_off[m] ^ (kh<<5))]);
      #pragma unroll
      for (int n = 0; n < 4; ++n)
        bfr[n] = __builtin_bit_cast(bf16x8, *(const uint4*)&Bs[bufo + (b_off[n] ^ (kh<<5))]);
      #pragma unroll
      for (int mt = 0; mt < 8; ++mt)
        #pragma unroll
        for (int nt = 0; nt < 4; ++nt)
          acc[mt][nt] = __builtin_amdgcn_mfma_f32_16x16x32_bf16(bfr[nt], af[mt], acc[mt][nt], 0,0,0);
    }
    __builtin_amdgcn_s_setprio(0);
  };
  #define SYNC asm volatile("s_waitcnt vmcnt(0)" ::: "memory"); __builtin_amdgcn_s_barrier();

  STAGE(0, 0);
  SYNC
  for (int s2 = 0; s2 < 2; ++s2){        // 4 K-steps
    STAGE(16384, 2*s2+1);
    COMPUTE(0);
    SYNC
    if (s2 < 1) STAGE(0, 2*s2+2);
    COMPUTE(16384);
    SYNC
  }
  u16* op = (u16*)out;
  #pragma unroll
  for (int nt = 0; nt < 4; ++nt){
    const int och4 = o0 + wn*64 + nt*16 + qd*4;
    #pragma unroll
    for (int mt = 0; mt < 8; ++mt){
      const int px = wm*128 + mt*16 + (lane&15);
      ushort4 s;
      s.x = f2bf(acc[mt][nt][0]); s.y = f2bf(acc[mt][nt][1]);
      s.z = f2bf(acc[mt][nt][2]); s.w = f2bf(acc[mt][nt][3]);
      *(ushort4*)&op[(size_t)(pg + px)*NO + och4] = s;
    }
  }
  #undef SYNC
}

// ---------------- final GEMM: out = [q ; qpos] x [Mb_b ; Wo] + bias, K=512 -----
__global__ __launch_bounds__(512, 2) void gemm_out(const u16* __restrict__ qkv,
    const u16* __restrict__ qpos, const u16* __restrict__ Mb,
    const u16* __restrict__ wo, const float* __restrict__ bias,
    float* __restrict__ out){
  __shared__ u16 As[32768];
  __shared__ u16 Bs[32768];
  const int t = threadIdx.x, w8 = t>>6, lane = t&63;
  const int idx = blockIdx.x;
  const int nb = (idx&7)*32 + (idx>>3);
  const int pg = nb*256;
  const int b = pg>>12, hw0 = pg&4095;
  const int dstb = w8*2048 + lane*8;
  const u16 *aQ[4], *aX[4], *bM[4], *bW[4];
  #pragma unroll
  for (int i = 0; i < 4; ++i){
    int G = (w8*4+i)*64 + lane;
    int p = G>>3, gs = (G&7) ^ (p&7);
    aQ[i] = qkv  + (size_t)(pg + p)*768 + gs*8;          // q slice, row stride 768
    aX[i] = qpos + (size_t)(pg + p)*256 + gs*8;
    bM[i] = Mb   + ((size_t)b*256 + p)*256 + gs*8;       // per-batch Mb
    bW[i] = wo   + (size_t)p*256 + gs*8;
  }
  const int wm = w8>>2, wn = w8&3;
  const int qd = lane>>4;
  int a_off[8], b_off[4];
  #pragma unroll
  for (int m = 0; m < 8; ++m){
    int p = wm*128 + m*16 + (lane&15);
    a_off[m] = p*64 + ((qd ^ (p&7)) << 3);
  }
  #pragma unroll
  for (int n = 0; n < 4; ++n){
    int r = wn*64 + n*16 + (lane&15);
    b_off[n] = r*64 + ((qd ^ (r&7)) << 3);
  }
  f32x4 acc[8][4];
  #pragma unroll
  for (int i=0;i<8;++i)
    #pragma unroll
    for (int j=0;j<4;++j) acc[i][j] = f32x4{0.f,0.f,0.f,0.f};

  auto STAGE = [&](const int bufo, const int s){
    #pragma unroll
    for (int i = 0; i < 4; ++i){
      const u16* sa = (s < 4) ? (aQ[i] + s*64)      : (aX[i] + (s-4)*64);
      const u16* sb = (s < 4) ? (bM[i] + s*64)      : (bW[i] + (s-4)*64);
      gl2lds16(sa, &As[bufo + dstb + i*512]);
      gl2lds16(sb, &Bs[bufo + dstb + i*512]);
    }
  };
  auto COMPUTE = [&](const int bufo){
    __builtin_amdgcn_s_setprio(1);
    #pragma unroll
    for (int kh = 0; kh < 2; ++kh){
      bf16x8 af[8], bfr[4];
      #pragma unroll
      for (int m = 0; m < 8; ++m)
        af[m] = __builtin_bit_cast(bf16x8, *(const uint4*)&As[bufo + (a_off[m] ^ (kh<<5))]);
      #pragma unroll
      for (int n = 0; n < 4; ++n)
        bfr[n] = __builtin_bit_cast(bf16x8, *(const uint4*)&Bs[bufo + (b_off[n] ^ (kh<<5))]);
      #pragma unroll
      for (int mt = 0; mt < 8; ++mt)
        #pragma unroll
        for (int nt = 0; nt < 4; ++nt)
          acc[mt][nt] = __builtin_amdgcn_mfma_f32_16x16x32_bf16(af[mt], bfr[nt], acc[mt][nt], 0,0,0);
    }
    __builtin_amdgcn_s_setprio(0);
  };
  #define SYNC asm volatile("s_waitcnt vmcnt(0)" ::: "memory"); __builtin_amdgcn_s_barrier();

  STAGE(0, 0);
  SYNC
  #pragma unroll
  for (int s2 = 0; s2 < 4; ++s2){        // 8 K-steps (K=512)
    STAGE(16384, 2*s2+1);
    COMPUTE(0);
    SYNC
    if (s2 < 3) STAGE(0, 2*s2+2);
    COMPUTE(16384);
    SYNC
  }
  const int col = lane&15, row_l = qd*4;
  #pragma unroll
  for (int nt = 0; nt < 4; ++nt){
    const int och = wn*64 + nt*16 + col;
    const float bo2 = bias[och];
    #pragma unroll
    for (int mt = 0; mt < 8; ++mt){
      const int pl = wm*128 + mt*16 + row_l;
      float4 v;
      v.x = acc[mt][nt][0]+bo2; v.y = acc[mt][nt][1]+bo2;
      v.z = acc[mt][nt][2]+bo2; v.w = acc[mt][nt][3]+bo2;
      *(float4*)&out[((size_t)b*256 + och)*HW + hw0 + pl] = v;
    }
  }
  #undef SYNC
}

__global__ void zero_cl(float* __restrict__ cl){
  cl[blockIdx.x*256 + threadIdx.x] = 0.f;   // zeros cl (131072) + S (4096)
}

// ---------------- lambda: cl'[b',i,o] = sum_n exp(k[n][i])*v[n][o]; S[b',i] = sum_n exp ----
__global__ __launch_bounds__(64) void lambda_kern(const u16* __restrict__ qkv,
                                                  float* __restrict__ cl,
                                                  float* __restrict__ S){
  __shared__ float Kl[64*36];
  __shared__ float Vl[64*36];
  const int t = threadIdx.x;
  const int bp = blockIdx.x, split = blockIdx.y;
  const int b = bp>>3, h = bp&7;
  const int ig = t&7, og = t>>3;
  float acc[4][4];
  float sacc[4] = {0.f,0.f,0.f,0.f};
  #pragma unroll
  for (int i=0;i<4;++i)
    #pragma unroll
    for (int j=0;j<4;++j) acc[i][j] = 0.f;
  for (int chunk = 0; chunk < 8; ++chunk){
    const int n = split*512 + chunk*64 + t;
    const u16* kp = qkv + (size_t)(b*HW + n)*768 + 256 + h*32;   // raw k
    const u16* vp = kp + 256;
    uint4 k4[4], v4[4];
    #pragma unroll
    for (int qq=0;qq<4;++qq){ k4[qq] = ((const uint4*)kp)[qq]; v4[qq] = ((const uint4*)vp)[qq]; }
    __syncthreads();
    #pragma unroll
    for (int qq=0;qq<4;++qq){
      float kv[8], vv[8]; unp8(k4[qq], kv); unp8(v4[qq], vv);
      #pragma unroll
      for (int e=0;e<8;++e) kv[e] = __expf(kv[e]);
      *(float4*)&Kl[t*36 + qq*8]     = float4{kv[0],kv[1],kv[2],kv[3]};
      *(float4*)&Kl[t*36 + qq*8 + 4] = float4{kv[4],kv[5],kv[6],kv[7]};
      *(float4*)&Vl[t*36 + qq*8]     = float4{vv[0],vv[1],vv[2],vv[3]};
      *(float4*)&Vl[t*36 + qq*8 + 4] = float4{vv[4],vv[5],vv[6],vv[7]};
    }
    __syncthreads();
    for (int p = 0; p < 64; ++p){
      float4 kf = *(const float4*)&Kl[p*36 + ig*4];
      float4 vf = *(const float4*)&Vl[p*36 + og*4];
      float kfa[4] = {kf.x,kf.y,kf.z,kf.w};
      float vfa[4] = {vf.x,vf.y,vf.z,vf.w};
      #pragma unroll
      for (int i=0;i<4;++i){
        sacc[i] += kfa[i];
        #pragma unroll
        for (int j=0;j<4;++j) acc[i][j] = fmaf(kfa[i], vfa[j], acc[i][j]);
      }
    }
  }
  #pragma unroll
  for (int i=0;i<4;++i)
    #pragma unroll
    for (int j=0;j<4;++j)
      atomicAdd(&cl[(size_t)bp*1024 + (ig*4+i)*32 + og*4+j], acc[i][j]);
  if (og == 0){
    #pragma unroll
    for (int i=0;i<4;++i) atomicAdd(&S[bp*32 + ig*4 + i], sacc[i]);
  }
}

// ---------------- Mb_b[of][h*32+i] = sum_o' wo[of][h*32+o'] * cl_bh[i][o'] / S --
__global__ __launch_bounds__(256) void mb_kern(const float* __restrict__ cl,
    const float* __restrict__ S, const float* __restrict__ out_w,
    u16* __restrict__ Mb){
  __shared__ float clS[1024];
  __shared__ float sinv[32];
  const int t = threadIdx.x;
  const int h = blockIdx.x & 7, b = blockIdx.x >> 3;
  const int bp = b*8 + h;
  for (int idx = t; idx < 1024; idx += 256)
    clS[idx] = cl[(size_t)bp*1024 + idx];
  if (t < 32) sinv[t] = 0.17677669529663687f / S[bp*32 + t];
  __syncthreads();
  float wrow[32];
  #pragma unroll
  for (int o = 0; o < 32; ++o) wrow[o] = out_w[t*256 + h*32 + o];
  u16 out16[32];
  #pragma unroll
  for (int i = 0; i < 32; ++i){
    float a = 0.f;
    #pragma unroll
    for (int o = 0; o < 32; ++o) a = fmaf(wrow[o], clS[i*32+o], a);
    out16[i] = f2bf(a * sinv[i]);
  }
  u16* mp = Mb + ((size_t)b*256 + t)*256 + h*32;
  #pragma unroll
  for (int g = 0; g < 4; ++g)
    ((uint4*)mp)[g] = *(uint4*)&out16[g*8];
}

// ---------------- depthwise-5x5 pos-lambda; writes qpos = q .* pos ----------------
// vt layout: [chg 0..3][hp 0..399][8 u16] -> granule idx = chg*400 + hp.
__global__ __launch_bounds__(256) void pos_combine(const u16* __restrict__ qkv,
    const float* __restrict__ rel, u16* __restrict__ res){
  __shared__ u16 vt[12800];
  __shared__ float relT[800];
  const int t = threadIdx.x;
  const int tile = blockIdx.x, h = blockIdx.y, b = blockIdx.z;
  const int x0 = (tile&3)*16, y0 = (tile>>2)*16;
  for (int idx = t; idx < 800; idx += 256){
    int tap = idx>>5, ch = idx&31;
    relT[idx] = rel[ch*25 + tap];
  }
  #pragma unroll
  for (int i = 0; i < 7; ++i){
    int idx = t + 256*i;
    if (idx < 1600){
      int hp = idx>>2, g = idx&3;
      int hy = hp/20, hx = hp - hy*20;
      int y = y0 + hy - 2, x = x0 + hx - 2;
      uint4 v = uint4{0,0,0,0};
      if ((unsigned)y < 64u && (unsigned)x < 64u)
        v = *(const uint4*)&qkv[(size_t)(b*HW + y*64 + x)*768 + 512 + h*32 + g*8];
      *(uint4*)&vt[(g*400 + hp)*8] = v;
    }
  }
  __syncthreads();
  const int py = t>>4, px = t&15;
  const int pix = b*HW + (y0+py)*64 + x0 + px;
  const u16* qp = qkv + (size_t)pix*768 + h*32;
  float qv[32];
  {
    uint4 q0 = ((const uint4*)qp)[0], q1 = ((const uint4*)qp)[1];
    uint4 q2 = ((const uint4*)qp)[2], q3 = ((const uint4*)qp)[3];
    unp8(q0, qv); unp8(q1, qv+8); unp8(q2, qv+16); unp8(q3, qv+24);
  }
  float outv[32];
  #pragma unroll
  for (int chg = 0; chg < 4; ++chg){
    float pos[8];
    #pragma unroll
    for (int j=0;j<8;++j) pos[j] = 0.f;
    #pragma unroll
    for (int dy = 0; dy < 5; ++dy)
      #pragma unroll
      for (int dx = 0; dx < 5; ++dx){
        int hp = (py+dy)*20 + px + dx;
        uint4 v4 = *(const uint4*)&vt[(chg*400 + hp)*8];
        float vv[8]; unp8(v4, vv);
        float4 r0 = *(const float4*)&relT[(dy*5+dx)*32 + chg*8];
        float4 r1 = *(const float4*)&relT[(dy*5+dx)*32 + chg*8 + 4];
        pos[0]=fmaf(r0.x, vv[0], pos[0]); pos[1]=fmaf(r0.y, vv[1], pos[1]);
        pos[2]=fmaf(r0.z, vv[2], pos[2]); pos[3]=fmaf(r0.w, vv[3], pos[3]);
        pos[4]=fmaf(r1.x, vv[4], pos[4]); pos[5]=fmaf(r1.y, vv[5], pos[5]);
        pos[6]=fmaf(r1.z, vv[6], pos[6]); pos[7]=fmaf(r1.w, vv[7], pos[7]);
      }
    #pragma unroll
    for (int j=0;j<8;++j) outv[chg*8+j] = qv[chg*8+j] * pos[j];
  }
  u16* rp = res + (size_t)pix*256 + h*32;
  #pragma unroll
  for (int g = 0; g < 4; ++g){
    uint4 o_;
    o_.x = pack2(outv[g*8+0], outv[g*8+1]);
    o_.y = pack2(outv[g*8+2], outv[g*8+3]);
    o_.z = pack2(outv[g*8+4], outv[g*8+5]);
    o_.w = pack2(outv[g*8+6], outv[g*8+7]);
    ((uint4*)rp)[g] = o_;
  }
}

extern "C" void kernel_launch(void* const* d_in, const int* in_sizes, int n_in,
                              void* d_out, int out_size, void* d_ws, size_t ws_size,
                              hipStream_t stream) {
  const float* src   = (const float*)d_in[0];
  const float* rel   = (const float*)d_in[1];
  const float* qkv_w = (const float*)d_in[2];
  const float* cpe_w = (const float*)d_in[3];
  const float* cpe_b = (const float*)d_in[4];
  const float* out_w = (const float*)d_in[5];
  const float* out_b = (const float*)d_in[6];
  char* ws = (char*)d_ws;
  u16*   qkv  = (u16*)(ws);
  u16*   xpad = (u16*)(ws);                    // aliased (dead after conv)
  u16*   xbuf = (u16*)(ws + 100663296);        // x, then qpos
  float* cl   = (float*)(ws + 134217728);
  float* S    = (float*)(ws + 134742016);
  u16*   wrb  = (u16*)(ws + 134758400);        // dead after conv
  u16*   wq   = (u16*)(ws + 135938048);        // dead after qkv gemm
  u16*   Mb   = (u16*)(ws + 134758400);        // aliases wrb+wq (written later)
  u16*   wo   = (u16*)(ws + 136855552);

  zero_border<<<dim3(520), dim3(256), 0, stream>>>(xpad);
  to_nhwc<<<dim3(64, 16), dim3(256), 0, stream>>>(src, xpad);
  repack_w<<<dim3(3328), dim3(256), 0, stream>>>(cpe_w, qkv_w, out_w, wrb, wq, wo);
  conv_mfma<<<dim3(256), dim3(512), 0, stream>>>(xpad, wrb, cpe_b, xbuf);
  gemm_mfma<768,3><<<dim3(768), dim3(512), 0, stream>>>(xbuf, wq, (void*)qkv);
  zero_cl<<<dim3(528), dim3(256), 0, stream>>>(cl);   // zeros cl + S (contiguous)
  lambda_kern<<<dim3(128, 8), dim3(64), 0, stream>>>(qkv, cl, S);
  mb_kern<<<dim3(128), dim3(256), 0, stream>>>(cl, S, out_w, Mb);
  pos_combine<<<dim3(16, 8, 16), dim3(256), 0, stream>>>(qkv, rel, xbuf);
  gemm_out<<<dim3(256), dim3(512), 0, stream>>>(qkv, xbuf, Mb, wo, out_b, (float*)d_out);
}